// Round 7
// baseline (431.766 us; speedup 1.0000x reference)
//
#include <hip/hip_runtime.h>
#include <hip/hip_bf16.h>

#define VOCAB 100000
#define DIM   512
#define BATCH 4096
#define SEQ   200
#define HID   256
#define OUTN  20

typedef __attribute__((ext_vector_type(8))) short short8;
typedef __attribute__((ext_vector_type(4))) float floatx4;

static __device__ __forceinline__ unsigned short f2bf(float f) {
    __hip_bfloat16 b = __float2bfloat16(f);
    return *(unsigned short*)&b;
}
static __device__ __forceinline__ float bf2f(unsigned short u) {
    unsigned int v = (unsigned int)u << 16;
    return *(float*)&v;
}

// ---------------------------------------------------------------------------
// Kernel 0: emb_table fp32 [VOCAB, 512] -> bf16 [VOCAB, 512]. Pure stream.
// NT loads on the fp32 source (never re-read); normal stores so the bf16
// table stays cache-resident for the gather.
// ---------------------------------------------------------------------------
__global__ __launch_bounds__(256) void k_cvt(
    const float* __restrict__ src, unsigned short* __restrict__ dst)
{
    const int n8 = VOCAB * DIM / 8;          // 6.4M groups of 8
    int i = blockIdx.x * 256 + threadIdx.x;
    const int stride = gridDim.x * 256;
    const floatx4* s4 = (const floatx4*)src;
    short8* d8 = (short8*)dst;
    for (; i < n8; i += stride) {
        const floatx4 a = __builtin_nontemporal_load(&s4[2 * i]);
        const floatx4 b = __builtin_nontemporal_load(&s4[2 * i + 1]);
        short8 o;
        o[0] = (short)f2bf(a[0]); o[1] = (short)f2bf(a[1]);
        o[2] = (short)f2bf(a[2]); o[3] = (short)f2bf(a[3]);
        o[4] = (short)f2bf(b[0]); o[5] = (short)f2bf(b[1]);
        o[6] = (short)f2bf(b[2]); o[7] = (short)f2bf(b[3]);
        d8[i] = o;
    }
}

// ---------------------------------------------------------------------------
// Kernel 1: gather+reduce over bf16 table. One block per batch row,
// 256 threads = 4 waves; each wave reads full 1KB rows (64 lanes x 16B) for
// its quarter of the tokens; cross-wave reduce via LDS. rep out in bf16.
// ---------------------------------------------------------------------------
__global__ __launch_bounds__(256) void k_reduce_bf(
    const unsigned short* __restrict__ embb, const int* __restrict__ x,
    const int* __restrict__ lengths, unsigned short* __restrict__ repb)
{
    const int b = blockIdx.x;
    const int t = threadIdx.x;
    const int w = t >> 6;            // wave 0..3
    const int lane = t & 63;

    __shared__ int sidx[SEQ];
    for (int i = t; i < SEQ; i += 256) sidx[i] = x[b * SEQ + i];
    __syncthreads();

    float s[8] = {0.f, 0.f, 0.f, 0.f, 0.f, 0.f, 0.f, 0.f};
    float m[8] = {-1e30f, -1e30f, -1e30f, -1e30f, -1e30f, -1e30f, -1e30f, -1e30f};

    const unsigned short* base = embb + lane * 8;   // lane's 8 columns
    const int i0 = w * (SEQ / 4);

#pragma unroll 5
    for (int i = i0; i < i0 + SEQ / 4; ++i) {
        const short8 v = *(const short8*)(base + (size_t)sidx[i] * DIM);
#pragma unroll
        for (int j = 0; j < 8; ++j) {
            const float f = bf2f((unsigned short)v[j]);
            s[j] += f;
            m[j] = fmaxf(m[j], f);
        }
    }

    __shared__ float red[4][2][DIM];   // [wave][sum|max][col] = 16 KB
#pragma unroll
    for (int j = 0; j < 8; ++j) {
        red[w][0][lane * 8 + j] = s[j];
        red[w][1][lane * 8 + j] = m[j];
    }
    __syncthreads();

    // 256 threads x 2 columns each
    const float inv = 1.0f / (float)lengths[b];
    const int c0 = t * 2;
    unsigned int mu = 0, xu = 0;
#pragma unroll
    for (int j = 0; j < 2; ++j) {
        const float sv = red[0][0][c0 + j] + red[1][0][c0 + j]
                       + red[2][0][c0 + j] + red[3][0][c0 + j];
        const float mv = fmaxf(fmaxf(red[0][1][c0 + j], red[1][1][c0 + j]),
                               fmaxf(red[2][1][c0 + j], red[3][1][c0 + j]));
        mu |= (unsigned int)f2bf(sv * inv) << (16 * j);
        xu |= (unsigned int)f2bf(mv)       << (16 * j);
    }
    unsigned short* row = repb + (size_t)b * (2 * DIM);
    *(unsigned int*)(row + c0)       = mu;   // cols [0,512)
    *(unsigned int*)(row + DIM + c0) = xu;   // cols [512,1024)
}

// ---------------------------------------------------------------------------
// Kernel 1 (fallback path, fp32 table): gather direct.
// ---------------------------------------------------------------------------
__global__ __launch_bounds__(128) void k_reduce(
    const float* __restrict__ emb, const int* __restrict__ x,
    const int* __restrict__ lengths, unsigned short* __restrict__ repb)
{
    const int b = blockIdx.x;
    const int t = threadIdx.x;

    __shared__ int sidx[SEQ];
    for (int i = t; i < SEQ; i += 128) sidx[i] = x[b * SEQ + i];
    __syncthreads();

    const float4* embv = (const float4*)emb;
    float4 s = make_float4(0.f, 0.f, 0.f, 0.f);
    float4 m = make_float4(-1e30f, -1e30f, -1e30f, -1e30f);

#pragma unroll 4
    for (int i = 0; i < SEQ; ++i) {
        const float4 v = embv[(size_t)sidx[i] * (DIM / 4) + t];
        s.x += v.x; s.y += v.y; s.z += v.z; s.w += v.w;
        m.x = fmaxf(m.x, v.x); m.y = fmaxf(m.y, v.y);
        m.z = fmaxf(m.z, v.z); m.w = fmaxf(m.w, v.w);
    }

    const float inv = 1.0f / (float)lengths[b];
    unsigned long long mu =
          (unsigned long long)f2bf(s.x * inv)
        | ((unsigned long long)f2bf(s.y * inv) << 16)
        | ((unsigned long long)f2bf(s.z * inv) << 32)
        | ((unsigned long long)f2bf(s.w * inv) << 48);
    unsigned long long xu =
          (unsigned long long)f2bf(m.x)
        | ((unsigned long long)f2bf(m.y) << 16)
        | ((unsigned long long)f2bf(m.z) << 32)
        | ((unsigned long long)f2bf(m.w) << 48);

    unsigned short* row = repb + (size_t)b * (2 * DIM);
    *(unsigned long long*)(row + 4 * t)       = mu;
    *(unsigned long long*)(row + DIM + 4 * t) = xu;
}

// ---------------------------------------------------------------------------
// Kernel 1b: W1 [1024, 256] fp32 -> W1T [256, 1024] bf16 (transpose+convert).
// ---------------------------------------------------------------------------
__global__ __launch_bounds__(256) void k_w1t(
    const float* __restrict__ W1, unsigned short* __restrict__ W1T)
{
    __shared__ unsigned short s[64][65];
    const int n0 = blockIdx.x * 64;
    const int k0 = blockIdx.y * 64;
    const int t = threadIdx.x;

#pragma unroll
    for (int i = 0; i < 4; ++i) {
        const int kk = (t >> 4) + i * 16;
        const int cc = (t & 15) * 4;
        const float4 v = *(const float4*)&W1[(size_t)(k0 + kk) * HID + n0 + cc];
        s[cc + 0][kk] = f2bf(v.x);
        s[cc + 1][kk] = f2bf(v.y);
        s[cc + 2][kk] = f2bf(v.z);
        s[cc + 3][kk] = f2bf(v.w);
    }
    __syncthreads();

#pragma unroll
    for (int i = 0; i < 4; ++i) {
        const int nn = (t >> 4) + i * 16;
        const int kq = (t & 15) * 4;
        unsigned long long u =
              (unsigned long long)s[nn][kq + 0]
            | ((unsigned long long)s[nn][kq + 1] << 16)
            | ((unsigned long long)s[nn][kq + 2] << 32)
            | ((unsigned long long)s[nn][kq + 3] << 48);
        *(unsigned long long*)&W1T[(size_t)(n0 + nn) * (2 * DIM) + k0 + kq] = u;
    }
}

// ---------------------------------------------------------------------------
// Kernel 2 (fused MLP): logits = relu(rep @ W1 + b1) @ W2 + b2.
// Block = 16 batch rows x FULL 256 hidden cols -> layer 2 needs no
// cross-block reduction; h lives in LDS only (no HBM round-trip).
// Grid 256 blocks (1/CU), 256 threads = 4 waves; wave wv owns h-cols
// [wv*64, wv*64+64) as 4 MFMA 16x16x32 n-tiles.
// Fragment maps (m89/m120): A[m=lane&15][k=(lane>>4)*8+j],
// B[n=lane&15][k=(lane>>4)*8+j], D: col=lane&15, row=(lane>>4)*4+reg.
// ---------------------------------------------------------------------------
#define MB 16
#define KPAD 36   // 32 + 4 shorts pad (72B row stride: distinct bank starts)

__global__ __launch_bounds__(256) void k_mlp(
    const unsigned short* __restrict__ repb,   // [4096][1024] bf16
    const unsigned short* __restrict__ w1t,    // [256][1024]  bf16
    const float* __restrict__ b1,
    const float* __restrict__ W2,              // [256][20] fp32
    const float* __restrict__ b2,
    float* __restrict__ outp)                  // [4096][20] fp32
{
    const int K = 2 * DIM;                 // 1024
    const int rowBase = blockIdx.x * MB;
    const int tid  = threadIdx.x;
    const int lane = tid & 63;
    const int wv   = tid >> 6;             // 0..3

    __shared__ unsigned short sA[MB][KPAD];     //  1.2 KB
    __shared__ unsigned short sB[HID][KPAD];    // 18.4 KB
    __shared__ float sh[MB][HID + 4];           // 16.6 KB
    __shared__ float swt[OUTN][HID + 4];        // 20.8 KB  (W2^T)
    __shared__ float sb2[OUTN];

    // stage W2^T + b2 once (consumed after the K-loop; many barriers between)
    for (int i = tid; i < HID * OUTN; i += 256) {
        const int k = i / OUTN, c = i - k * OUTN;
        swt[c][k] = W2[i];
    }
    if (tid < OUTN) sb2[tid] = b2[tid];

    // A staging: threads 0..63, r = tid>>2 (0..15), kq = tid&3 (short8 each)
    const int ar  = tid >> 2;
    const int akq = tid & 3;
    const bool aldr = (tid < 64);
    const unsigned short* gA = repb + (size_t)(rowBase + (aldr ? ar : 0)) * K + akq * 8;
    // B staging: thread t = hidden col n, 4 short8 (64B contiguous)
    const short8* gB = (const short8*)(w1t + (size_t)tid * K);

    floatx4 acc[4] = {{0.f,0.f,0.f,0.f},{0.f,0.f,0.f,0.f},
                      {0.f,0.f,0.f,0.f},{0.f,0.f,0.f,0.f}};

    short8 pa = aldr ? *(const short8*)gA : short8{};
    short8 pb0 = gB[0], pb1 = gB[1], pb2 = gB[2], pb3 = gB[3];

    const int lm = lane & 15;
    const int lq = lane >> 4;
    for (int k0 = 0; k0 < K; k0 += 32) {
        __syncthreads();
        if (aldr) *(short8*)&sA[ar][akq * 8] = pa;
        *(short8*)&sB[tid][0]  = pb0;
        *(short8*)&sB[tid][8]  = pb1;
        *(short8*)&sB[tid][16] = pb2;
        *(short8*)&sB[tid][24] = pb3;
        __syncthreads();

        if (k0 + 32 < K) {
            if (aldr) pa = *(const short8*)(gA + k0 + 32);
            const int g = (k0 + 32) >> 3;
            pb0 = gB[g]; pb1 = gB[g + 1]; pb2 = gB[g + 2]; pb3 = gB[g + 3];
        }

        const short8 a = *(const short8*)&sA[lm][lq * 8];
#pragma unroll
        for (int nt = 0; nt < 4; ++nt) {
            const short8 bfrag = *(const short8*)&sB[wv * 64 + nt * 16 + lm][lq * 8];
            acc[nt] = __builtin_amdgcn_mfma_f32_16x16x32_bf16(a, bfrag, acc[nt], 0, 0, 0);
        }
    }

    // Epilogue 1: bias + relu into LDS h
#pragma unroll
    for (int nt = 0; nt < 4; ++nt) {
        const int col = wv * 64 + nt * 16 + lm;
        const float bb = b1[col];
#pragma unroll
        for (int rg = 0; rg < 4; ++rg)
            sh[lq * 4 + rg][col] = fmaxf(acc[nt][rg] + bb, 0.f);
    }
    __syncthreads();

    // Epilogue 2: 16x20 logits from LDS; float4 k-loop
#pragma unroll
    for (int o = tid; o < MB * OUTN; o += 256) {
        const int r = o / OUTN;
        const int c = o - r * OUTN;
        float a0 = sb2[c];
#pragma unroll 8
        for (int k = 0; k < HID; k += 4) {
            const float4 hv = *(const float4*)&sh[r][k];
            const float4 wvv = *(const float4*)&swt[c][k];
            a0 += hv.x * wvv.x + hv.y * wvv.y + hv.z * wvv.z + hv.w * wvv.w;
        }
        outp[(size_t)(rowBase + r) * OUTN + c] = a0;
    }
}

// ---------------------------------------------------------------------------
extern "C" void kernel_launch(void* const* d_in, const int* in_sizes, int n_in,
                              void* d_out, int out_size, void* d_ws, size_t ws_size,
                              hipStream_t stream)
{
    const float* emb     = (const float*)d_in[0];
    const float* W1      = (const float*)d_in[1];
    const float* b1      = (const float*)d_in[2];
    const float* W2      = (const float*)d_in[3];
    const float* b2      = (const float*)d_in[4];
    const int*   x       = (const int*)d_in[5];
    const int*   lengths = (const int*)d_in[6];

    float* out = (float*)d_out;

    const size_t embbN = (size_t)VOCAB * DIM;            // bf16 elems, 102.4 MB
    const size_t repbN = (size_t)BATCH * 2 * DIM;        // bf16 elems,   8.4 MB
    const size_t w1tN  = (size_t)HID * 2 * DIM;          // bf16 elems,   0.5 MB
    const size_t needFast = (embbN + repbN + w1tN) * 2 + 256;

    if (ws_size >= needFast) {
        unsigned short* embb = (unsigned short*)d_ws;
        unsigned short* repb = embb + embbN;
        unsigned short* w1t  = repb + repbN;

        k_cvt<<<2048, 256, 0, stream>>>(emb, embb);
        k_w1t<<<dim3(HID / 64, (2 * DIM) / 64), 256, 0, stream>>>(W1, w1t);
        k_reduce_bf<<<BATCH, 256, 0, stream>>>(embb, x, lengths, repb);
        k_mlp<<<BATCH / MB, 256, 0, stream>>>(repb, w1t, b1, W2, b2, out);
    } else {
        unsigned short* repb = (unsigned short*)d_ws;
        unsigned short* w1t  = repb + repbN;

        k_w1t<<<dim3(HID / 64, (2 * DIM) / 64), 256, 0, stream>>>(W1, w1t);
        k_reduce<<<BATCH, 128, 0, stream>>>(emb, x, lengths, repb);
        k_mlp<<<BATCH / MB, 256, 0, stream>>>(repb, w1t, b1, W2, b2, out);
    }
}